// Round 12
// baseline (137.757 us; speedup 1.0000x reference)
//
#include <hip/hip_runtime.h>
#include <hip/hip_bf16.h>
#include <math.h>

// Problem constants (B=1)
#define SEQ    4096
#define DMODEL 1024
#define NHEADS 8
#define DH     64
#define DINNER 512      // NHEADS*DH
#define NQKV   1536     // 3*DINNER
#define WINDOW 128
#define PERSIST 4
#define EPS 1.1920929e-07f

// Padded K-strides (elements) — R8 measured optimum (G0 ~32us vs 39 @1024, 44.5 @1152).
#define XLD  1032   // x and wqkv_bt row stride (K = 1024)
#define ALD  520    // att and wout_bt row stride (K = 512)

typedef unsigned short u16;
typedef unsigned int   u32;
typedef __bf16  bf16_8 __attribute__((ext_vector_type(8)));
typedef float   f32x4  __attribute__((ext_vector_type(4)));

__device__ __forceinline__ u16 f2b(float f) {
    union { float f; u32 i; } v; v.f = f;
    u32 i = v.i;
    u32 r = (i + 0x7fffu + ((i >> 16) & 1u)) >> 16;   // round-to-nearest-even
    return (u16)r;
}

// async 16B global->LDS (lane i of the wave lands at ldsbase + i*16)
#define GLD16(gp, lp) __builtin_amdgcn_global_load_lds( \
    (const __attribute__((address_space(1))) void*)(gp), \
    (__attribute__((address_space(3))) void*)(lp), 16, 0, 0)

// ---------------- prep: weight transposes (fp32->bf16, PADDED dst stride) + RMSNorm ----------------
__device__ __forceinline__ void transpose_tile(const float* __restrict__ src,
                                               u16* __restrict__ dst,
                                               int DLD, int N, int bn, int bk,
                                               u16 (*t)[65], int tid) {
    int r = tid >> 4, c4 = (tid & 15) * 4;
    #pragma unroll
    for (int it = 0; it < 4; it++) {
        int row = r + it * 16;
        float4 v = *(const float4*)(src + (size_t)(bk + row) * N + bn + c4);
        t[row][c4 + 0] = f2b(v.x);
        t[row][c4 + 1] = f2b(v.y);
        t[row][c4 + 2] = f2b(v.z);
        t[row][c4 + 3] = f2b(v.w);
    }
    __syncthreads();
    #pragma unroll
    for (int it = 0; it < 4; it++) {
        int n = r + it * 16;
        u16* d = dst + (size_t)(bn + n) * DLD + bk + c4;
        uint2 o;
        o.x = (u32)t[c4 + 0][n] | ((u32)t[c4 + 1][n] << 16);
        o.y = (u32)t[c4 + 2][n] | ((u32)t[c4 + 3][n] << 16);
        *(uint2*)d = o;   // 8B aligned: DLD even, bk+c4 multiple of 4
    }
}

__global__ __launch_bounds__(256) void prep_kernel(const float* __restrict__ wqkv,
                                                   const float* __restrict__ wout,
                                                   const float* __restrict__ seq,
                                                   const float* __restrict__ g,
                                                   u16* __restrict__ wqkv_bt,
                                                   u16* __restrict__ wout_bt,
                                                   u16* __restrict__ x) {
    __shared__ u16 t[64][65];
    __shared__ float wsum[4];
    int b = blockIdx.x, tid = threadIdx.x;
    if (b < 384) {
        transpose_tile(wqkv, wqkv_bt, XLD, NQKV, (b % 24) * 64, (b / 24) * 64, t, tid);
    } else if (b < 512) {
        int bb = b - 384;
        transpose_tile(wout, wout_bt, ALD, DMODEL, (bb % 16) * 64, (bb / 16) * 64, t, tid);
    } else {
        int row = b - 512;
        float4 v = *(const float4*)(seq + (size_t)row * DMODEL + tid * 4);
        float ss = v.x*v.x + v.y*v.y + v.z*v.z + v.w*v.w;
        #pragma unroll
        for (int o = 32; o > 0; o >>= 1) ss += __shfl_xor(ss, o);
        if ((tid & 63) == 0) wsum[tid >> 6] = ss;
        __syncthreads();
        float tot = wsum[0] + wsum[1] + wsum[2] + wsum[3];
        float rstd = rsqrtf(tot * (1.0f / DMODEL) + EPS);
        float4 gv = *(const float4*)(g + tid * 4);
        uint2 o;
        o.x = (u32)f2b(v.x * rstd * gv.x) | ((u32)f2b(v.y * rstd * gv.y) << 16);
        o.y = (u32)f2b(v.z * rstd * gv.z) | ((u32)f2b(v.w * rstd * gv.w) << 16);
        *(uint2*)(x + (size_t)row * XLD + tid * 4) = o;
    }
}

// ---------------- QKV GEMM: 128x192 tile, 512 threads, 2 blocks/CU, dbuf + counted vmcnt ----------------
// G0 is bound by per-CU load-issue BW (~11 B/cyc/CU, m13): R8's 128x96 stages 224MB; this tile
// stages 160MB (8MB*8 + 3MB*32). LDS 80KB -> exactly 2 blocks/CU = 16 waves/CU (R7's mistake was
// this tile at 1 block/CU = 8 waves, latency-exposed). No XCD swizzle (R10: lockstep L2 sharing
// wins). K-sweep order identical to R8 -> bit-identical accumulation.
__global__ __launch_bounds__(512, 4) void gemm_qkv(const u16* __restrict__ A,
                                                   const u16* __restrict__ Bt,
                                                   u16* __restrict__ C0,
                                                   u16* __restrict__ C1,
                                                   u16* __restrict__ C2) {
    __shared__ u16 As[2][128 * 64];   // 32 KB
    __shared__ u16 Bs[2][192 * 64];   // 48 KB  (80 KB total -> 2 blocks/CU)
    int bx = blockIdx.x, by = blockIdx.y, tid = threadIdx.x;
    int lane = tid & 63, wave = tid >> 6;      // 8 waves: 2 (M) x 4 (N)
    int m16 = lane & 15, quad = lane >> 4;
    int rw0 = (wave & 1) * 64, cw0 = (wave >> 1) * 48;

    f32x4 acc[4][3];
    #pragma unroll
    for (int mt = 0; mt < 4; mt++)
        #pragma unroll
        for (int nt = 0; nt < 3; nt++) acc[mt][nt] = (f32x4){0.f, 0.f, 0.f, 0.f};

    int lrow = lane & 7, lkc = lane >> 3;
    const u16* Ag = A  + (size_t)(by * 128 + lrow) * XLD + lkc * 8;
    const u16* Bg = Bt + (size_t)(bx * 192 + lrow) * XLD + lkc * 8;

    // stage: A 16 groups (2/wave) + B 24 groups (3/wave) of 8rows x 64k = 1KB each; 5 loads/thread
    auto stage_tile = [&](int tt, int bb) {
        int k0 = tt * 64;
        #pragma unroll
        for (int r = 0; r < 2; r++) {
            int gg = wave * 2 + r;
            GLD16(Ag + (size_t)(gg * 8) * XLD + k0, &As[bb][0] + gg * 512);
        }
        #pragma unroll
        for (int r = 0; r < 3; r++) {
            int gg = wave * 3 + r;
            GLD16(Bg + (size_t)(gg * 8) * XLD + k0, &Bs[bb][0] + gg * 512);
        }
    };
    auto compute_tile = [&](int bb) {
        #pragma unroll
        for (int kk = 0; kk < 2; kk++) {
            int kc = kk * 4 + quad;
            bf16_8 afr[4], bfr[3];
            #pragma unroll
            for (int mt = 0; mt < 4; mt++) {
                int row = rw0 + mt * 16 + m16;
                afr[mt] = *(const bf16_8*)(&As[bb][0] + (row >> 3) * 512 + kc * 64 + (row & 7) * 8);
            }
            #pragma unroll
            for (int nt = 0; nt < 3; nt++) {
                int col = cw0 + nt * 16 + m16;
                bfr[nt] = *(const bf16_8*)(&Bs[bb][0] + (col >> 3) * 512 + kc * 64 + (col & 7) * 8);
            }
            #pragma unroll
            for (int mt = 0; mt < 4; mt++)
                #pragma unroll
                for (int nt = 0; nt < 3; nt++)
                    acc[mt][nt] = __builtin_amdgcn_mfma_f32_16x16x32_bf16(afr[mt], bfr[nt], acc[mt][nt], 0, 0, 0);
        }
    };

    stage_tile(0, 0);
    #pragma unroll 1
    for (int t = 0; t < 15; t++) {                     // 16 K-steps total
        int cur = t & 1;
        stage_tile(t + 1, cur ^ 1);                    // prefetch next; loads stay in flight
        asm volatile("s_waitcnt vmcnt(5)" ::: "memory");   // cur's 5 loads resident (never 0)
        __builtin_amdgcn_s_barrier();
        __builtin_amdgcn_sched_barrier(0);
        compute_tile(cur);
        __builtin_amdgcn_s_barrier();                  // all readers done -> next iter may overwrite
    }
    asm volatile("s_waitcnt vmcnt(0)" ::: "memory");
    __builtin_amdgcn_s_barrier();
    __builtin_amdgcn_sched_barrier(0);
    compute_tile(1);

    // epilogue: C/D layout row=quad*4+r, col=lane&15; 16-col run never straddles a head boundary
    #pragma unroll
    for (int nt = 0; nt < 3; nt++) {
        int col = bx * 192 + cw0 + nt * 16 + m16;
        int tens = col >> 9, hh = (col >> 6) & 7, dh = col & 63;
        if (tens == 2) {
            // V: transposed [h][d][n]; r=0..3 are n-contiguous -> one 8B store per (mt,nt)
            #pragma unroll
            for (int mt = 0; mt < 4; mt++) {
                int nb = by * 128 + rw0 + mt * 16 + quad * 4;
                uint2 o;
                o.x = (u32)f2b(acc[mt][nt][0]) | ((u32)f2b(acc[mt][nt][1]) << 16);
                o.y = (u32)f2b(acc[mt][nt][2]) | ((u32)f2b(acc[mt][nt][3]) << 16);
                *(uint2*)(C2 + ((size_t)(hh * DH + dh)) * SEQ + nb) = o;
            }
        } else {
            // q,k: row-major [h][n][64] with fused RoPE
            int tt = (col & 63) >> 1;
            float inv = exp2f(-(float)(2 * tt) * (13.287712379549449f / 64.0f));
            bool odd = (col & 1);
            u16* dst = (tens == 0) ? C0 : C1;
            #pragma unroll
            for (int mt = 0; mt < 4; mt++) {
                #pragma unroll
                for (int r = 0; r < 4; r++) {
                    int row = by * 128 + rw0 + mt * 16 + quad * 4 + r;
                    float own = acc[mt][nt][r];
                    float part = __shfl_xor(own, 1);
                    float s, c;
                    __sincosf((float)row * inv, &s, &c);
                    float val = odd ? (own * c + part * s) : (own * c - part * s);
                    dst[((size_t)hh * SEQ + row) * DH + dh] = f2b(val);
                }
            }
        }
    }
}

// ---------------- out-proj GEMM: 128x64, 256 threads, dbuf + counted vmcnt (R8 shape) ----------------
__global__ __launch_bounds__(256, 2) void gemm_out(const u16* __restrict__ A,
                                                   const u16* __restrict__ Bt,
                                                   float* __restrict__ Cf) {
    constexpr int BN = 64, GPW = 2, NT = DINNER / 64;
    __shared__ u16 As[2][128 * 64];
    __shared__ u16 Bs[2][BN * 64];
    int bx = blockIdx.x, by = blockIdx.y, tid = threadIdx.x;
    int lane = tid & 63, wave = tid >> 6;
    int m16 = lane & 15, quad = lane >> 4;
    int rw0 = (wave & 1) * 64, cw0 = (wave >> 1) * 32;

    f32x4 acc[4][2];
    #pragma unroll
    for (int mt = 0; mt < 4; mt++)
        #pragma unroll
        for (int nt = 0; nt < 2; nt++) acc[mt][nt] = (f32x4){0.f, 0.f, 0.f, 0.f};

    int lrow = lane & 7, lkc = lane >> 3;
    const u16* Ag = A  + (size_t)(by * 128 + lrow) * ALD + lkc * 8;
    const u16* Bg = Bt + (size_t)(bx * BN  + lrow) * ALD + lkc * 8;

    auto stage_tile = [&](int tt, int bb) {
        int k0 = tt * 64;
        #pragma unroll
        for (int r = 0; r < 4; r++) {
            int gg = wave * 4 + r;
            GLD16(Ag + (size_t)(gg * 8) * ALD + k0, &As[bb][0] + gg * 512);
        }
        #pragma unroll
        for (int r = 0; r < GPW; r++) {
            int gg = wave * GPW + r;
            GLD16(Bg + (size_t)(gg * 8) * ALD + k0, &Bs[bb][0] + gg * 512);
        }
    };
    auto compute_tile = [&](int bb) {
        #pragma unroll
        for (int kk = 0; kk < 2; kk++) {
            int kc = kk * 4 + quad;
            bf16_8 afr[4], bfr[2];
            #pragma unroll
            for (int mt = 0; mt < 4; mt++) {
                int row = rw0 + mt * 16 + m16;
                afr[mt] = *(const bf16_8*)(&As[bb][0] + (row >> 3) * 512 + kc * 64 + (row & 7) * 8);
            }
            #pragma unroll
            for (int nt = 0; nt < 2; nt++) {
                int col = cw0 + nt * 16 + m16;
                bfr[nt] = *(const bf16_8*)(&Bs[bb][0] + (col >> 3) * 512 + kc * 64 + (col & 7) * 8);
            }
            #pragma unroll
            for (int mt = 0; mt < 4; mt++)
                #pragma unroll
                for (int nt = 0; nt < 2; nt++)
                    acc[mt][nt] = __builtin_amdgcn_mfma_f32_16x16x32_bf16(afr[mt], bfr[nt], acc[mt][nt], 0, 0, 0);
        }
    };

    stage_tile(0, 0);
    #pragma unroll 1
    for (int t = 0; t < NT - 1; t++) {
        int cur = t & 1;
        stage_tile(t + 1, cur ^ 1);
        asm volatile("s_waitcnt vmcnt(6)" ::: "memory");
        __builtin_amdgcn_s_barrier();
        __builtin_amdgcn_sched_barrier(0);
        compute_tile(cur);
        __builtin_amdgcn_s_barrier();
    }
    asm volatile("s_waitcnt vmcnt(0)" ::: "memory");
    __builtin_amdgcn_s_barrier();
    __builtin_amdgcn_sched_barrier(0);
    compute_tile((NT - 1) & 1);

    #pragma unroll
    for (int nt = 0; nt < 2; nt++) {
        int col = bx * BN + cw0 + nt * 16 + m16;
        #pragma unroll
        for (int mt = 0; mt < 4; mt++) {
            #pragma unroll
            for (int r = 0; r < 4; r++) {
                int row = by * 128 + rw0 + mt * 16 + quad * 4 + r;
                Cf[(size_t)row * DMODEL + col] = acc[mt][nt][r];
            }
        }
    }
}

// ---------------- Attention: MFMA flash-style, Vt layout for b128 PV reads ----------------
#define AROWS 208
#define KLD2  72      // Ks row stride (u16)
#define PLD   168     // Ps row stride (u16)
#define VLD   222     // Vt row stride (u16): 444B spreads banks (~4-way worst)

__global__ __launch_bounds__(256, 2) void attn_mfma(const u16* __restrict__ Q,
                                                    const u16* __restrict__ Kt,
                                                    const u16* __restrict__ Vg,   // [h][d][n] transposed
                                                    u16* __restrict__ O) {       // [n][ALD] padded
    __shared__ __align__(16) char smem[29952 + 64 * VLD * 2];
    u16* Ks = (u16*)smem;                       // [208][72]
    u16* Ps = (u16*)smem;                       // [4*16][168]  (after barrier)
    u16* Vt = (u16*)(smem + 29952);             // [64][222]    d-major
    int i0 = blockIdx.x * 64, h = blockIdx.y;
    int tid = threadIdx.x, wave = tid >> 6, lane = tid & 63;
    int m16 = lane & 15, quad = lane >> 4;
    int smin = (i0 > WINDOW) ? i0 - WINDOW : 0;

    // K rows: row-major b128 copy
    for (int idx = tid; idx < AROWS * 8; idx += 256) {
        int row = idx >> 3, c = idx & 7;
        int j = (row < 16) ? row : (smin + row - 16);
        *(bf16_8*)(Ks + row * KLD2 + c * 8) =
            *(const bf16_8*)(Kt + ((size_t)h * SEQ + j) * DH + c * 8);
    }
    // V: source already transposed [h][d][n] -> plain b128 global + b128 LDS write
    for (int idx = tid; idx < 64 * 26; idx += 256) {
        int d = idx / 26, c = idx - d * 26;
        int t0 = c * 8;
        int n0 = (c < 2) ? t0 : (smin + t0 - 16);
        *(bf16_8*)(Vt + d * VLD + t0) =
            *(const bf16_8*)(Vg + ((size_t)(h * DH + d)) * SEQ + n0);
    }

    int iw0 = i0 + wave * 16;
    int iq = iw0 + m16;
    const u16* qrow = Q + ((size_t)h * SEQ + iq) * DH;
    bf16_8 qa = *(const bf16_8*)(qrow + quad * 8);
    bf16_8 qb = *(const bf16_8*)(qrow + 32 + quad * 8);
    __syncthreads();

    int start_w = (iw0 > WINDOW) ? iw0 - WINDOW : 0;
    int Dw = start_w - smin;
    int tlast = 31 + iw0 - start_w;
    int nch = (tlast >> 4) + 1;                  // <=10
    int nk32 = (tlast >> 5) + 1;                 // <=5

    // ---- QK^T (reads Ks) ----
    f32x4 S[10];
    __builtin_amdgcn_s_setprio(1);
    #pragma unroll
    for (int c = 0; c < 10; c++) {
        if (c < nch) {
            int t = c * 16 + m16;
            int row = (c == 0) ? t : (t + Dw);
            const u16* kp = Ks + row * KLD2;
            bf16_8 kb0 = *(const bf16_8*)(kp + quad * 8);
            bf16_8 kb1 = *(const bf16_8*)(kp + 32 + quad * 8);
            f32x4 s = (f32x4){0.f, 0.f, 0.f, 0.f};
            s = __builtin_amdgcn_mfma_f32_16x16x32_bf16(qa, kb0, s, 0, 0, 0);
            s = __builtin_amdgcn_mfma_f32_16x16x32_bf16(qb, kb1, s, 0, 0, 0);
            S[c] = s;
        }
    }
    __builtin_amdgcn_s_setprio(0);
    __syncthreads();   // Ks dead after this point; Ps may now overwrite it

    // ---- mask + softmax (registers only) ----
    float mrow[4] = {-1e30f, -1e30f, -1e30f, -1e30f};
    #pragma unroll
    for (int c = 0; c < 10; c++) {
        if (c < nch) {
            int t = c * 16 + m16;
            int j = (c == 0) ? t : (start_w + t - 16);
            #pragma unroll
            for (int r = 0; r < 4; r++) {
                int i = iw0 + quad * 4 + r;
                bool valid = (c == 0) ? (j < PERSIST && j < start_w)
                                      : (j <= i && (i - j <= WINDOW || j < PERSIST));
                float sv = valid ? S[c][r] * 0.125f : -1e30f;
                S[c][r] = sv;
                mrow[r] = fmaxf(mrow[r], sv);
            }
        }
    }
    #pragma unroll
    for (int r = 0; r < 4; r++) {
        #pragma unroll
        for (int o = 1; o < 16; o <<= 1) mrow[r] = fmaxf(mrow[r], __shfl_xor(mrow[r], o));
    }
    float srow[4] = {0.f, 0.f, 0.f, 0.f};
    #pragma unroll
    for (int c = 0; c < 10; c++) {
        if (c < nch) {
            #pragma unroll
            for (int r = 0; r < 4; r++) {
                float p = __expf(S[c][r] - mrow[r]);
                S[c][r] = p;
                srow[r] += p;
            }
        }
    }
    #pragma unroll
    for (int r = 0; r < 4; r++) {
        #pragma unroll
        for (int o = 1; o < 16; o <<= 1) srow[r] += __shfl_xor(srow[r], o);
    }

    // ---- P -> LDS (C layout -> A layout); zero-fill unused ----
    u16* pw = Ps + wave * 16 * PLD;
    #pragma unroll
    for (int c = 0; c < 10; c++) {
        #pragma unroll
        for (int r = 0; r < 4; r++) {
            u16 val = (c < nch) ? f2b(S[c][r]) : (u16)0;
            pw[(quad * 4 + r) * PLD + c * 16 + m16] = val;
        }
    }

    // ---- PV: A from Ps (b128), B from Vt (b128) ----
    f32x4 oacc[4];
    #pragma unroll
    for (int nt = 0; nt < 4; nt++) oacc[nt] = (f32x4){0.f, 0.f, 0.f, 0.f};
    __builtin_amdgcn_s_setprio(1);
    #pragma unroll
    for (int c2 = 0; c2 < 5; c2++) {
        if (c2 < nk32) {
            bf16_8 af = *(const bf16_8*)(pw + m16 * PLD + c2 * 32 + quad * 8);
            int kbase = c2 * 32 + quad * 8;
            int rowb = (kbase < 16) ? kbase : (kbase + Dw);
            #pragma unroll
            for (int nt = 0; nt < 4; nt++) {
                int d = nt * 16 + m16;
                bf16_8 bv = *(const bf16_8*)(Vt + d * VLD + rowb);
                oacc[nt] = __builtin_amdgcn_mfma_f32_16x16x32_bf16(af, bv, oacc[nt], 0, 0, 0);
            }
        }
    }
    __builtin_amdgcn_s_setprio(0);

    float rinv[4];
    #pragma unroll
    for (int r = 0; r < 4; r++) rinv[r] = 1.0f / srow[r];
    #pragma unroll
    for (int nt = 0; nt < 4; nt++) {
        #pragma unroll
        for (int r = 0; r < 4; r++) {
            int i = iw0 + quad * 4 + r;
            O[(size_t)i * ALD + h * DH + nt * 16 + m16] = f2b(oacc[nt][r] * rinv[r]);
        }
    }
}

// ---------------- launch ----------------
extern "C" void kernel_launch(void* const* d_in, const int* in_sizes, int n_in,
                              void* d_out, int out_size, void* d_ws, size_t ws_size,
                              hipStream_t stream) {
    const float* seq  = (const float*)d_in[0];   // fp32 inputs
    const float* g    = (const float*)d_in[1];
    const float* wqkv = (const float*)d_in[2];
    const float* wout = (const float*)d_in[3];
    float* out = (float*)d_out;                   // fp32 output

    char* ws = (char*)d_ws;
    u16* x       = (u16*)(ws);                            // [4096][1032] bf16 = 8.06 MB
    u16* q       = (u16*)(ws + 9ll  * 1024 * 1024);       // 4 MB   [h][n][64]
    u16* k       = (u16*)(ws + 13ll * 1024 * 1024);       // 4 MB   [h][n][64]
    u16* v       = (u16*)(ws + 17ll * 1024 * 1024);       // 4 MB   [h][64][n] (transposed)
    u16* att     = (u16*)(ws + 21ll * 1024 * 1024);       // [4096][520] bf16 = 4.06 MB
    u16* wqkv_bt = (u16*)(ws + 26ll * 1024 * 1024);       // [1536][1032] bf16 = 3.02 MB
    u16* wout_bt = (u16*)(ws + 30ll * 1024 * 1024);       // [1024][520]  bf16 = 1.02 MB

    prep_kernel<<<4608, 256, 0, stream>>>(wqkv, wout, seq, g, wqkv_bt, wout_bt, x);

    // QKV: 128x192 tiles, 512 threads -> grid 8x32 = 256 blocks, 80KB LDS -> 2 blocks/CU,
    // 16 waves/CU. Staged bytes 224 -> 160 MB at the same occupancy as R8's best.
    dim3 g1(NQKV / 192, SEQ / 128);
    gemm_qkv<<<g1, 512, 0, stream>>>(x, wqkv_bt, q, k, v);

    dim3 g2(SEQ / 64, NHEADS);
    attn_mfma<<<g2, 256, 0, stream>>>(q, k, v, att);

    // out: 128x64 tiles -> 512 blocks (2/CU); unchanged R8 shape
    dim3 g3(DMODEL / 64, SEQ / 128);
    gemm_out<<<g3, 256, 0, stream>>>(att, wout_bt, out);
}

// Round 13
// 131.736 us; speedup vs baseline: 1.0457x; 1.0457x over previous
//
#include <hip/hip_runtime.h>
#include <hip/hip_bf16.h>
#include <math.h>

// Problem constants (B=1)
#define SEQ    4096
#define DMODEL 1024
#define NHEADS 8
#define DH     64
#define DINNER 512      // NHEADS*DH
#define NQKV   1536     // 3*DINNER
#define WINDOW 128
#define PERSIST 4
#define EPS 1.1920929e-07f

// Padded K-strides (elements) — R8 measured optimum (G0 ~32us vs 39 @1024, 44.5 @1152).
#define XLD  1032   // x and wqkv_bt row stride (K = 1024)
#define ALD  520    // att and wout_bt row stride (K = 512)

typedef unsigned short u16;
typedef unsigned int   u32;
typedef __bf16  bf16_8 __attribute__((ext_vector_type(8)));
typedef float   f32x4  __attribute__((ext_vector_type(4)));

__device__ __forceinline__ u16 f2b(float f) {
    union { float f; u32 i; } v; v.f = f;
    u32 i = v.i;
    u32 r = (i + 0x7fffu + ((i >> 16) & 1u)) >> 16;   // round-to-nearest-even
    return (u16)r;
}

// async 16B global->LDS (lane i of the wave lands at ldsbase + i*16)
#define GLD16(gp, lp) __builtin_amdgcn_global_load_lds( \
    (const __attribute__((address_space(1))) void*)(gp), \
    (__attribute__((address_space(3))) void*)(lp), 16, 0, 0)

// ---------------- prep: weight transposes (fp32->bf16, PADDED dst stride) + RMSNorm ----------------
__device__ __forceinline__ void transpose_tile(const float* __restrict__ src,
                                               u16* __restrict__ dst,
                                               int DLD, int N, int bn, int bk,
                                               u16 (*t)[65], int tid) {
    int r = tid >> 4, c4 = (tid & 15) * 4;
    #pragma unroll
    for (int it = 0; it < 4; it++) {
        int row = r + it * 16;
        float4 v = *(const float4*)(src + (size_t)(bk + row) * N + bn + c4);
        t[row][c4 + 0] = f2b(v.x);
        t[row][c4 + 1] = f2b(v.y);
        t[row][c4 + 2] = f2b(v.z);
        t[row][c4 + 3] = f2b(v.w);
    }
    __syncthreads();
    #pragma unroll
    for (int it = 0; it < 4; it++) {
        int n = r + it * 16;
        u16* d = dst + (size_t)(bn + n) * DLD + bk + c4;
        uint2 o;
        o.x = (u32)t[c4 + 0][n] | ((u32)t[c4 + 1][n] << 16);
        o.y = (u32)t[c4 + 2][n] | ((u32)t[c4 + 3][n] << 16);
        *(uint2*)d = o;   // 8B aligned: DLD even, bk+c4 multiple of 4
    }
}

__global__ __launch_bounds__(256) void prep_kernel(const float* __restrict__ wqkv,
                                                   const float* __restrict__ wout,
                                                   const float* __restrict__ seq,
                                                   const float* __restrict__ g,
                                                   u16* __restrict__ wqkv_bt,
                                                   u16* __restrict__ wout_bt,
                                                   u16* __restrict__ x) {
    __shared__ u16 t[64][65];
    __shared__ float wsum[4];
    int b = blockIdx.x, tid = threadIdx.x;
    if (b < 384) {
        transpose_tile(wqkv, wqkv_bt, XLD, NQKV, (b % 24) * 64, (b / 24) * 64, t, tid);
    } else if (b < 512) {
        int bb = b - 384;
        transpose_tile(wout, wout_bt, ALD, DMODEL, (bb % 16) * 64, (bb / 16) * 64, t, tid);
    } else {
        int row = b - 512;
        float4 v = *(const float4*)(seq + (size_t)row * DMODEL + tid * 4);
        float ss = v.x*v.x + v.y*v.y + v.z*v.z + v.w*v.w;
        #pragma unroll
        for (int o = 32; o > 0; o >>= 1) ss += __shfl_xor(ss, o);
        if ((tid & 63) == 0) wsum[tid >> 6] = ss;
        __syncthreads();
        float tot = wsum[0] + wsum[1] + wsum[2] + wsum[3];
        float rstd = rsqrtf(tot * (1.0f / DMODEL) + EPS);
        float4 gv = *(const float4*)(g + tid * 4);
        uint2 o;
        o.x = (u32)f2b(v.x * rstd * gv.x) | ((u32)f2b(v.y * rstd * gv.y) << 16);
        o.y = (u32)f2b(v.z * rstd * gv.z) | ((u32)f2b(v.w * rstd * gv.w) << 16);
        *(uint2*)(x + (size_t)row * XLD + tid * 4) = o;
    }
}

// ---------------- 128xBN MFMA GEMM: BK=64 dbuf, prefetch + counted vmcnt, optional XCD chunking ----------------
// KLD = padded row stride of A and Bt (elements); staging reads only k in [0, KTOT).
// SWZ=1 (G0 only): hardware round-robins linear block id over the 8 XCDs (lin%8 = XCD), so the
// 16 blocks sharing an A-panel land on 8 DIFFERENT XCDs and every panel is replicated into all
// L2s -> staging is served by the ~7 TB/s cross-die path (R8: 224MB/32us, FETCH only 34MB).
// swz=(lin&7)*64+(lin>>3) gives XCD j the 64 blocks {by in [4j,4j+4), all bx}: per-XCD set =
// 4 A-panels (1MB) + B (3MB) = 4MB = one L2 -> staging streams from the LOCAL L2 (~4.3TB/s/XCD).
// Lockstep K-sweep preserved (R10: decorrelation hurts). Pure block renaming: bit-identical C.
template <int MODE, int NTW, int KTOT, int KLD, int SWZ>
__global__ __launch_bounds__(256, 2) void gemm2_kernel(const u16* __restrict__ A,
                                                       const u16* __restrict__ Bt,
                                                       u16* __restrict__ C0,
                                                       u16* __restrict__ C1,
                                                       u16* __restrict__ C2,
                                                       float* __restrict__ Cf) {
    constexpr int BN  = NTW * 32;     // block N width (96 or 64)
    constexpr int GPW = BN / 32;      // B 8-row groups per wave (3 or 2)
    constexpr int NT  = KTOT / 64;    // K-steps (16 or 8)
    __shared__ u16 As[2][128 * 64];   // 2 x 16 KB
    __shared__ u16 Bs[2][BN * 64];    // 2 x 12 or 8 KB
    int bx, by;
    if constexpr (SWZ) {
        int lin = blockIdx.y * 16 + blockIdx.x;     // grid 16 x 32 = 512
        int swz = (lin & 7) * 64 + (lin >> 3);      // bijective: 512 % 8 == 0
        bx = swz & 15; by = swz >> 4;
    } else {
        bx = blockIdx.x; by = blockIdx.y;
    }
    int tid = threadIdx.x;
    int lane = tid & 63, wave = tid >> 6;
    int m16 = lane & 15, quad = lane >> 4;
    int rw0 = (wave & 1) * 64, cw0 = (wave >> 1) * (NTW * 16);

    f32x4 acc[4][NTW];
    #pragma unroll
    for (int mt = 0; mt < 4; mt++)
        #pragma unroll
        for (int nt = 0; nt < NTW; nt++) acc[mt][nt] = (f32x4){0.f, 0.f, 0.f, 0.f};

    int lrow = lane & 7, lkc = lane >> 3;
    const u16* Ag = A  + (size_t)(by * 128 + lrow) * KLD + lkc * 8;
    const u16* Bg = Bt + (size_t)(bx * BN  + lrow) * KLD + lkc * 8;

    auto stage_tile = [&](int tt, int bb) {
        int k0 = tt * 64;
        #pragma unroll
        for (int r = 0; r < 4; r++) {
            int gg = wave * 4 + r;
            GLD16(Ag + (size_t)(gg * 8) * KLD + k0, &As[bb][0] + gg * 512);
        }
        #pragma unroll
        for (int r = 0; r < GPW; r++) {
            int gg = wave * GPW + r;
            GLD16(Bg + (size_t)(gg * 8) * KLD + k0, &Bs[bb][0] + gg * 512);
        }
    };
    auto compute_tile = [&](int bb) {
        #pragma unroll
        for (int kk = 0; kk < 2; kk++) {
            int kc = kk * 4 + quad;
            bf16_8 afr[4], bfr[NTW];
            #pragma unroll
            for (int mt = 0; mt < 4; mt++) {
                int row = rw0 + mt * 16 + m16;
                afr[mt] = *(const bf16_8*)(&As[bb][0] + (row >> 3) * 512 + kc * 64 + (row & 7) * 8);
            }
            #pragma unroll
            for (int nt = 0; nt < NTW; nt++) {
                int col = cw0 + nt * 16 + m16;
                bfr[nt] = *(const bf16_8*)(&Bs[bb][0] + (col >> 3) * 512 + kc * 64 + (col & 7) * 8);
            }
            #pragma unroll
            for (int mt = 0; mt < 4; mt++)
                #pragma unroll
                for (int nt = 0; nt < NTW; nt++)
                    acc[mt][nt] = __builtin_amdgcn_mfma_f32_16x16x32_bf16(afr[mt], bfr[nt], acc[mt][nt], 0, 0, 0);
        }
    };

    stage_tile(0, 0);
    #pragma unroll 1
    for (int t = 0; t < NT - 1; t++) {
        int cur = t & 1;
        stage_tile(t + 1, cur ^ 1);                    // prefetch next; loads stay in flight
        if constexpr (NTW == 3) asm volatile("s_waitcnt vmcnt(7)" ::: "memory");
        else                    asm volatile("s_waitcnt vmcnt(6)" ::: "memory");
        __builtin_amdgcn_s_barrier();
        __builtin_amdgcn_sched_barrier(0);
        compute_tile(cur);
        __builtin_amdgcn_s_barrier();                  // all readers done -> next iter may overwrite
    }
    asm volatile("s_waitcnt vmcnt(0)" ::: "memory");
    __builtin_amdgcn_s_barrier();
    __builtin_amdgcn_sched_barrier(0);
    compute_tile((NT - 1) & 1);

    // epilogue: C/D layout row=quad*4+r, col=lane&15
    #pragma unroll
    for (int nt = 0; nt < NTW; nt++) {
        int col = bx * BN + cw0 + nt * 16 + m16;
        if (MODE == 0) {
            int tens = col >> 9, hh = (col >> 6) & 7, dh = col & 63;
            if (tens == 2) {
                // V: transposed [h][d][n]; r=0..3 are n-contiguous -> one 8B store per (mt,nt)
                #pragma unroll
                for (int mt = 0; mt < 4; mt++) {
                    int nb = by * 128 + rw0 + mt * 16 + quad * 4;
                    uint2 o;
                    o.x = (u32)f2b(acc[mt][nt][0]) | ((u32)f2b(acc[mt][nt][1]) << 16);
                    o.y = (u32)f2b(acc[mt][nt][2]) | ((u32)f2b(acc[mt][nt][3]) << 16);
                    *(uint2*)(C2 + ((size_t)(hh * DH + dh)) * SEQ + nb) = o;
                }
            } else {
                // q,k: row-major [h][n][64] with fused RoPE
                int tt = (col & 63) >> 1;
                float inv = exp2f(-(float)(2 * tt) * (13.287712379549449f / 64.0f));
                bool odd = (col & 1);
                u16* dst = (tens == 0) ? C0 : C1;
                #pragma unroll
                for (int mt = 0; mt < 4; mt++) {
                    #pragma unroll
                    for (int r = 0; r < 4; r++) {
                        int row = by * 128 + rw0 + mt * 16 + quad * 4 + r;
                        float own = acc[mt][nt][r];
                        float part = __shfl_xor(own, 1);
                        float s, c;
                        __sincosf((float)row * inv, &s, &c);
                        float val = odd ? (own * c + part * s) : (own * c - part * s);
                        dst[((size_t)hh * SEQ + row) * DH + dh] = f2b(val);
                    }
                }
            }
        } else {
            #pragma unroll
            for (int mt = 0; mt < 4; mt++) {
                #pragma unroll
                for (int r = 0; r < 4; r++) {
                    int row = by * 128 + rw0 + mt * 16 + quad * 4 + r;
                    Cf[(size_t)row * DMODEL + col] = acc[mt][nt][r];
                }
            }
        }
    }
}

// ---------------- Attention: MFMA flash-style, Vt layout for b128 PV reads ----------------
#define AROWS 208
#define KLD2  72      // Ks row stride (u16)
#define PLD   168     // Ps row stride (u16)
#define VLD   222     // Vt row stride (u16): 444B spreads banks (~4-way worst)

__global__ __launch_bounds__(256, 2) void attn_mfma(const u16* __restrict__ Q,
                                                    const u16* __restrict__ Kt,
                                                    const u16* __restrict__ Vg,   // [h][d][n] transposed
                                                    u16* __restrict__ O) {       // [n][ALD] padded
    __shared__ __align__(16) char smem[29952 + 64 * VLD * 2];
    u16* Ks = (u16*)smem;                       // [208][72]
    u16* Ps = (u16*)smem;                       // [4*16][168]  (after barrier)
    u16* Vt = (u16*)(smem + 29952);             // [64][222]    d-major
    int i0 = blockIdx.x * 64, h = blockIdx.y;
    int tid = threadIdx.x, wave = tid >> 6, lane = tid & 63;
    int m16 = lane & 15, quad = lane >> 4;
    int smin = (i0 > WINDOW) ? i0 - WINDOW : 0;

    // K rows: row-major b128 copy
    for (int idx = tid; idx < AROWS * 8; idx += 256) {
        int row = idx >> 3, c = idx & 7;
        int j = (row < 16) ? row : (smin + row - 16);
        *(bf16_8*)(Ks + row * KLD2 + c * 8) =
            *(const bf16_8*)(Kt + ((size_t)h * SEQ + j) * DH + c * 8);
    }
    // V: source already transposed [h][d][n] -> plain b128 global + b128 LDS write
    for (int idx = tid; idx < 64 * 26; idx += 256) {
        int d = idx / 26, c = idx - d * 26;
        int t0 = c * 8;
        int n0 = (c < 2) ? t0 : (smin + t0 - 16);
        *(bf16_8*)(Vt + d * VLD + t0) =
            *(const bf16_8*)(Vg + ((size_t)(h * DH + d)) * SEQ + n0);
    }

    int iw0 = i0 + wave * 16;
    int iq = iw0 + m16;
    const u16* qrow = Q + ((size_t)h * SEQ + iq) * DH;
    bf16_8 qa = *(const bf16_8*)(qrow + quad * 8);
    bf16_8 qb = *(const bf16_8*)(qrow + 32 + quad * 8);
    __syncthreads();

    int start_w = (iw0 > WINDOW) ? iw0 - WINDOW : 0;
    int Dw = start_w - smin;
    int tlast = 31 + iw0 - start_w;
    int nch = (tlast >> 4) + 1;                  // <=10
    int nk32 = (tlast >> 5) + 1;                 // <=5

    // ---- QK^T (reads Ks) ----
    f32x4 S[10];
    __builtin_amdgcn_s_setprio(1);
    #pragma unroll
    for (int c = 0; c < 10; c++) {
        if (c < nch) {
            int t = c * 16 + m16;
            int row = (c == 0) ? t : (t + Dw);
            const u16* kp = Ks + row * KLD2;
            bf16_8 kb0 = *(const bf16_8*)(kp + quad * 8);
            bf16_8 kb1 = *(const bf16_8*)(kp + 32 + quad * 8);
            f32x4 s = (f32x4){0.f, 0.f, 0.f, 0.f};
            s = __builtin_amdgcn_mfma_f32_16x16x32_bf16(qa, kb0, s, 0, 0, 0);
            s = __builtin_amdgcn_mfma_f32_16x16x32_bf16(qb, kb1, s, 0, 0, 0);
            S[c] = s;
        }
    }
    __builtin_amdgcn_s_setprio(0);
    __syncthreads();   // Ks dead after this point; Ps may now overwrite it

    // ---- mask + softmax (registers only) ----
    float mrow[4] = {-1e30f, -1e30f, -1e30f, -1e30f};
    #pragma unroll
    for (int c = 0; c < 10; c++) {
        if (c < nch) {
            int t = c * 16 + m16;
            int j = (c == 0) ? t : (start_w + t - 16);
            #pragma unroll
            for (int r = 0; r < 4; r++) {
                int i = iw0 + quad * 4 + r;
                bool valid = (c == 0) ? (j < PERSIST && j < start_w)
                                      : (j <= i && (i - j <= WINDOW || j < PERSIST));
                float sv = valid ? S[c][r] * 0.125f : -1e30f;
                S[c][r] = sv;
                mrow[r] = fmaxf(mrow[r], sv);
            }
        }
    }
    #pragma unroll
    for (int r = 0; r < 4; r++) {
        #pragma unroll
        for (int o = 1; o < 16; o <<= 1) mrow[r] = fmaxf(mrow[r], __shfl_xor(mrow[r], o));
    }
    float srow[4] = {0.f, 0.f, 0.f, 0.f};
    #pragma unroll
    for (int c = 0; c < 10; c++) {
        if (c < nch) {
            #pragma unroll
            for (int r = 0; r < 4; r++) {
                float p = __expf(S[c][r] - mrow[r]);
                S[c][r] = p;
                srow[r] += p;
            }
        }
    }
    #pragma unroll
    for (int r = 0; r < 4; r++) {
        #pragma unroll
        for (int o = 1; o < 16; o <<= 1) srow[r] += __shfl_xor(srow[r], o);
    }

    // ---- P -> LDS (C layout -> A layout); zero-fill unused ----
    u16* pw = Ps + wave * 16 * PLD;
    #pragma unroll
    for (int c = 0; c < 10; c++) {
        #pragma unroll
        for (int r = 0; r < 4; r++) {
            u16 val = (c < nch) ? f2b(S[c][r]) : (u16)0;
            pw[(quad * 4 + r) * PLD + c * 16 + m16] = val;
        }
    }

    // ---- PV: A from Ps (b128), B from Vt (b128) ----
    f32x4 oacc[4];
    #pragma unroll
    for (int nt = 0; nt < 4; nt++) oacc[nt] = (f32x4){0.f, 0.f, 0.f, 0.f};
    __builtin_amdgcn_s_setprio(1);
    #pragma unroll
    for (int c2 = 0; c2 < 5; c2++) {
        if (c2 < nk32) {
            bf16_8 af = *(const bf16_8*)(pw + m16 * PLD + c2 * 32 + quad * 8);
            int kbase = c2 * 32 + quad * 8;
            int rowb = (kbase < 16) ? kbase : (kbase + Dw);
            #pragma unroll
            for (int nt = 0; nt < 4; nt++) {
                int d = nt * 16 + m16;
                bf16_8 bv = *(const bf16_8*)(Vt + d * VLD + rowb);
                oacc[nt] = __builtin_amdgcn_mfma_f32_16x16x32_bf16(af, bv, oacc[nt], 0, 0, 0);
            }
        }
    }
    __builtin_amdgcn_s_setprio(0);

    float rinv[4];
    #pragma unroll
    for (int r = 0; r < 4; r++) rinv[r] = 1.0f / srow[r];
    #pragma unroll
    for (int nt = 0; nt < 4; nt++) {
        #pragma unroll
        for (int r = 0; r < 4; r++) {
            int i = iw0 + quad * 4 + r;
            O[(size_t)i * ALD + h * DH + nt * 16 + m16] = f2b(oacc[nt][r] * rinv[r]);
        }
    }
}

// ---------------- launch ----------------
extern "C" void kernel_launch(void* const* d_in, const int* in_sizes, int n_in,
                              void* d_out, int out_size, void* d_ws, size_t ws_size,
                              hipStream_t stream) {
    const float* seq  = (const float*)d_in[0];   // fp32 inputs
    const float* g    = (const float*)d_in[1];
    const float* wqkv = (const float*)d_in[2];
    const float* wout = (const float*)d_in[3];
    float* out = (float*)d_out;                   // fp32 output

    char* ws = (char*)d_ws;
    u16* x       = (u16*)(ws);                            // [4096][1032] bf16 = 8.06 MB
    u16* q       = (u16*)(ws + 9ll  * 1024 * 1024);       // 4 MB   [h][n][64]
    u16* k       = (u16*)(ws + 13ll * 1024 * 1024);       // 4 MB   [h][n][64]
    u16* v       = (u16*)(ws + 17ll * 1024 * 1024);       // 4 MB   [h][64][n] (transposed)
    u16* att     = (u16*)(ws + 21ll * 1024 * 1024);       // [4096][520] bf16 = 4.06 MB
    u16* wqkv_bt = (u16*)(ws + 26ll * 1024 * 1024);       // [1536][1032] bf16 = 3.02 MB
    u16* wout_bt = (u16*)(ws + 30ll * 1024 * 1024);       // [1024][520]  bf16 = 1.02 MB

    prep_kernel<<<4608, 256, 0, stream>>>(wqkv, wout, seq, g, wqkv_bt, wout_bt, x);

    // QKV: 128x96 tiles -> 512 blocks (2/CU); dbuf prefetch, counted vmcnt(7);
    // + XCD-chunked swizzle: each XCD owns {4 consecutive by} x all bx -> 4MB L2-resident set
    dim3 g1(NQKV / 96, SEQ / 128);
    gemm2_kernel<0, 3, DMODEL, XLD, 1><<<g1, 256, 0, stream>>>(x, wqkv_bt, q, k, v, nullptr);

    dim3 g2(SEQ / 64, NHEADS);
    attn_mfma<<<g2, 256, 0, stream>>>(q, k, v, att);

    // out: 128x64 tiles -> 512 blocks (2/CU); unchanged R8 shape (no swizzle)
    dim3 g3(DMODEL / 64, SEQ / 128);
    gemm2_kernel<1, 2, DINNER, ALD, 0><<<g3, 256, 0, stream>>>(att, wout_bt, nullptr, nullptr, nullptr, out);
}